// Round 1
// baseline (48.676 us; speedup 1.0000x reference)
//
#include <hip/hip_runtime.h>

// Problem constants (B=4, C=4, H=64, W=64, K=8192)
static constexpr int TOKENS = 16384;   // B*H*W
static constexpr int HW     = 4096;    // H*W
static constexpr int KCB    = 8192;    // codebook entries
static constexpr int NSLICE = 32;      // codebook slices
static constexpr int SLICE  = 256;     // entries per slice (NSLICE*SLICE == KCB)
static constexpr int NGROUP = 16;      // token groups
static constexpr int GTOK   = 1024;    // tokens per group
static constexpr int TPT    = 4;       // tokens per thread in dist kernel

// ---------------- Kernel 1: pre-quant 1x1 conv -> token vectors ----------------
__global__ __launch_bounds__(256) void k_prep(
    const float* __restrict__ z,      // [B,C,H,W]
    const float* __restrict__ w,      // [C_out, C_in] = [4,4]
    const float* __restrict__ bias,   // [4]
    float4* __restrict__ X,           // [TOKENS]
    float* __restrict__ acc)          // loss accumulator (zeroed here)
{
    int t = blockIdx.x * 256 + threadIdx.x;
    if (t == 0) *acc = 0.0f;
    if (t >= TOKENS) return;
    int b = t >> 12;          // 4096 tokens per batch image
    int n = t & (HW - 1);
    const float* zb = z + b * (4 * HW) + n;
    float z0 = zb[0], z1 = zb[HW], z2 = zb[2 * HW], z3 = zb[3 * HW];
    float4 x;
    x.x = fmaf(w[3],  z3, fmaf(w[2],  z2, fmaf(w[1],  z1, fmaf(w[0],  z0, bias[0]))));
    x.y = fmaf(w[7],  z3, fmaf(w[6],  z2, fmaf(w[5],  z1, fmaf(w[4],  z0, bias[1]))));
    x.z = fmaf(w[11], z3, fmaf(w[10], z2, fmaf(w[9],  z1, fmaf(w[8],  z0, bias[2]))));
    x.w = fmaf(w[15], z3, fmaf(w[14], z2, fmaf(w[13], z1, fmaf(w[12], z0, bias[3]))));
    X[t] = x;
}

// ---------------- Kernel 2: sliced distance argmin (the heavy one) -------------
__global__ __launch_bounds__(256, 2) void k_dist(
    const float4* __restrict__ X,    // [TOKENS]
    const float4* __restrict__ CB,   // [KCB]
    float* __restrict__ Pv,          // [NSLICE * TOKENS] partial min values
    unsigned* __restrict__ Pi)       // [NSLICE * TOKENS] partial argmin indices
{
    __shared__ float4 cbs[SLICE];
    __shared__ float  cns[SLICE];
    const int bx  = blockIdx.x;
    const int g   = bx & (NGROUP - 1);   // token group
    const int s   = bx >> 4;             // codebook slice (NGROUP == 16)
    const int tid = threadIdx.x;

    // Stage this slice of the codebook + squared norms into LDS.
    {
        float4 c = CB[s * SLICE + tid];
        cbs[tid] = c;
        float cn = c.x * c.x;
        cn = fmaf(c.y, c.y, cn);
        cn = fmaf(c.z, c.z, cn);
        cn = fmaf(c.w, c.w, cn);
        cns[tid] = cn;
    }
    __syncthreads();

    const int tbase = g * GTOK + tid;
    float m0[TPT], m1[TPT], m2[TPT], m3[TPT];
    float bv[TPT];
    int   bi[TPT];
#pragma unroll
    for (int j = 0; j < TPT; ++j) {
        float4 x = X[tbase + j * 256];
        m0[j] = -2.0f * x.x;
        m1[j] = -2.0f * x.y;
        m2[j] = -2.0f * x.z;
        m3[j] = -2.0f * x.w;
        bv[j] = 3.0e38f;
        bi[j] = 0;
    }

    // score = |c|^2 - 2 x.c  (per-token |x|^2 is constant -> argmin-invariant)
    for (int e = 0; e < SLICE; ++e) {
        float4 c  = cbs[e];     // all lanes same address -> LDS broadcast
        float  cn = cns[e];
#pragma unroll
        for (int j = 0; j < TPT; ++j) {
            float d = fmaf(m0[j], c.x, cn);
            d = fmaf(m1[j], c.y, d);
            d = fmaf(m2[j], c.z, d);
            d = fmaf(m3[j], c.w, d);
            if (d < bv[j]) { bv[j] = d; bi[j] = e; }  // strict < keeps lowest idx
        }
    }

#pragma unroll
    for (int j = 0; j < TPT; ++j) {
        int t = tbase + j * 256;
        Pv[s * TOKENS + t] = bv[j];
        Pi[s * TOKENS + t] = (unsigned)(s * SLICE + bi[j]);
    }
}

// ---------------- Kernel 3: final reduce + gather + output + loss partial ------
__global__ __launch_bounds__(256) void k_out(
    const float4* __restrict__ X,
    const float4* __restrict__ CB,
    const float* __restrict__ Pv,
    const unsigned* __restrict__ Pi,
    float* __restrict__ out,         // [B,C,H,W]
    float* __restrict__ acc)
{
    int t = blockIdx.x * 256 + threadIdx.x;
    float bv = 3.0e38f;
    unsigned bi = 0;
#pragma unroll 8
    for (int s = 0; s < NSLICE; ++s) {
        float v    = Pv[s * TOKENS + t];
        unsigned i = Pi[s * TOKENS + t];
        if (v < bv) { bv = v; bi = i; }  // ascending slice order -> lowest idx on ties
    }
    float4 x = X[t];
    float4 q = CB[bi];
    int b = t >> 12;
    int n = t & (HW - 1);
    float* ob = out + b * (4 * HW) + n;
    float d0 = q.x - x.x;
    float d1 = q.y - x.y;
    float d2 = q.z - x.z;
    float d3 = q.w - x.w;
    // straight-through: x + (q - x), same rounding as reference
    ob[0]      = x.x + d0;
    ob[HW]     = x.y + d1;
    ob[2 * HW] = x.z + d2;
    ob[3 * HW] = x.w + d3;

    float ls = d0 * d0 + d1 * d1 + d2 * d2 + d3 * d3;
#pragma unroll
    for (int off = 32; off > 0; off >>= 1)
        ls += __shfl_down(ls, off, 64);
    __shared__ float wsum[4];
    if ((threadIdx.x & 63) == 0) wsum[threadIdx.x >> 6] = ls;
    __syncthreads();
    if (threadIdx.x == 0)
        atomicAdd(acc, wsum[0] + wsum[1] + wsum[2] + wsum[3]);
}

// ---------------- Kernel 4: finalize loss --------------------------------------
__global__ void k_loss(const float* __restrict__ acc, float* __restrict__ out)
{
    float m = acc[0] * (1.0f / 65536.0f);   // mean over B*N*C = 65536 elements
    out[TOKENS * 4] = m + 0.25f * m;        // codebook_loss + BETA * commitment
}

extern "C" void kernel_launch(void* const* d_in, const int* in_sizes, int n_in,
                              void* d_out, int out_size, void* d_ws, size_t ws_size,
                              hipStream_t stream)
{
    const float* z    = (const float*)d_in[0];
    const float* w    = (const float*)d_in[1];
    const float* bias = (const float*)d_in[2];
    const float* cb   = (const float*)d_in[3];
    float* out = (float*)d_out;

    // Workspace layout (16B-aligned chunks)
    char* ws = (char*)d_ws;
    float*    acc = (float*)ws;                            // 4 B
    float4*   X   = (float4*)(ws + 1024);                  // 256 KiB
    float*    Pv  = (float*)(ws + 1024 + 262144);          // 2 MiB
    unsigned* Pi  = (unsigned*)(ws + 1024 + 262144 + 2097152); // 2 MiB

    const float4* CB4 = (const float4*)cb;

    k_prep<<<TOKENS / 256, 256, 0, stream>>>(z, w, bias, X, acc);
    k_dist<<<NSLICE * NGROUP, 256, 0, stream>>>(X, CB4, Pv, Pi);
    k_out<<<TOKENS / 256, 256, 0, stream>>>(X, CB4, Pv, Pi, out, acc);
    k_loss<<<1, 1, 0, stream>>>(acc, out);
}